// Round 5
// baseline (136.610 us; speedup 1.0000x reference)
//
#include <hip/hip_runtime.h>
#include <math.h>

// DotProductAttention B=64,S=1024,D=64 fp32, bf16-MFMA flash attention.
// Round 7: RESUBMIT of round-6 (container infra failure, no kernel signal).
// De-alias batch->CU mapping. Round-5's split-K changed NOTHING
// (54.0 vs 53.8us) -> smoking gun: under round-robin dispatch (block i ->
// XCD i%8, CU (i/8)%32), co-resident blocks on a CU are 256 apart in
// blockIdx, and 256 % 64 == 0, so with b = blockIdx&63 ALL blocks on a CU
// share one batch (same vl). Per-CU work was invariant under split-K
// (4x16 = 8x8 = 64 block-iters on the straggler CU) and makespan = worst
// batch, occupancy ~ mean/max ~ 19%. Fix: skew the decode,
//   b = (g&63 + g>>6) & 63
// so same-CU blocks (g spaced 256 -> grp +4) hit batches 4 apart: per-CU
// work becomes a mean over 8 distinct batches (34 +/- 7 block-iters vs 64).
// Split-K structure unchanged (proven correct rounds 3-5):
//   kernel1 (2048 blocks): halves; vl<=512 -> direct-write fast path.
//   kernel2 (1024 blocks): combines it_full>8 pairs.
// LDS 18.4 KB; VGPR 64; no fences/atomics (round-4 lesson: __threadfence
// on gfx950 = buffer_wbl2/inv = ~400us of TCC stalls).

#define BATCH 64
#define SEQ   1024
#define DIM   64
#define BQ    64           // queries per block (4 waves x 16)
#define BC    64           // keys per iteration
#define NKT   (SEQ / BC)   // 16
#define HALFT 8            // K-tiles per split-K item
#define LSTR  72           // LDS row stride in bf16 (144 B = 36 dwords === 4 mod 32)
#define QSCALE 0.18033688011112442f   // 0.125 * log2(e)
#define MASKED -1.0e6f

// workspace layout
#define WS_LM_SZ   (2048 * 64 * 8)              // float2 (m,l) per query per item = 1 MB
#define WS_O_OFF   WS_LM_SZ                     // 1048576
#define WS_O_SZ    (2048 * 4096 * 4)            // 32 MB of partial O
#define WS_NEEDED  ((size_t)WS_O_OFF + (size_t)WS_O_SZ)

typedef __attribute__((ext_vector_type(8))) short bf16x8;
typedef __attribute__((ext_vector_type(4))) float f32x4;

__device__ __forceinline__ uint pack2_trunc(float lo, float hi) {
    // [bf16(hi) : bf16(lo)] by byte-select (truncation) — one v_perm_b32
    return __builtin_amdgcn_perm(__float_as_uint(hi), __float_as_uint(lo), 0x07060302);
}
__device__ __forceinline__ ushort f2bf_rne(float x) {
    uint u = __float_as_uint(x);
    return (ushort)((u + 0x7fffu + ((u >> 16) & 1u)) >> 16);
}

__global__ __launch_bounds__(256, 4) void attn_mfma_splitk(
    const float* __restrict__ q, const float* __restrict__ k,
    const float* __restrict__ v, const int* __restrict__ valid_lens,
    float* __restrict__ out,
    float2* __restrict__ lmbuf, float* __restrict__ opart)
{
    __shared__ ushort KPs[BC * LSTR];   // K tile; after barrier C, P tile (alias)
    __shared__ ushort Vt[DIM * LSTR];   // [d][key]

    const int t    = threadIdx.x;
    const int wave = t >> 6;
    const int wl   = t & 63;
    const int QD   = wl >> 4;          // quad 0..3
    const int li   = wl & 15;          // lane-in-quad 0..15
    // skewed decode: co-resident blocks (blockIdx spaced 256 = grp+4) get
    // DIFFERENT batches -> per-CU work averages over 8 batches.
    const int g    = blockIdx.x;
    const int grp  = g >> 6;           // 0..31 = (qt, half)
    const int b    = ((g & 63) + grp) & 63;
    const int half = grp & 1;
    const int qt   = grp >> 1;
    const int q0   = qt * BQ;
    const int pid  = (qt << 6) | b;    // 0..1023
    const int item = pid * 2 + half;
    const int vl   = valid_lens[b];

    const size_t boff = (size_t)b * SEQ * DIM;

    const int it_full  = (vl == 0) ? NKT : ((vl + BC - 1) >> 6);
    const int it_begin = half * HALFT;
    const int it_end   = min(it_full, it_begin + HALFT);

    if (it_begin >= it_end) return;    // empty second half: partner direct-writes

    const bool direct = (half == 0) && (it_full <= HALFT);  // own the whole range

    // ---- Q fragments straight into registers (B-operand), pre-scaled ----
    bf16x8 qb[2];
    {
        const float* qrow = q + boff + (size_t)(q0 + wave * 16 + li) * DIM + QD * 8;
        #pragma unroll
        for (int kc = 0; kc < 2; kc++) {
            float4 a = *(const float4*)(qrow + kc * 32);
            float4 c = *(const float4*)(qrow + kc * 32 + 4);
            union { bf16x8 v; ushort u[8]; } tmp;
            tmp.u[0] = f2bf_rne(a.x * QSCALE);
            tmp.u[1] = f2bf_rne(a.y * QSCALE);
            tmp.u[2] = f2bf_rne(a.z * QSCALE);
            tmp.u[3] = f2bf_rne(a.w * QSCALE);
            tmp.u[4] = f2bf_rne(c.x * QSCALE);
            tmp.u[5] = f2bf_rne(c.y * QSCALE);
            tmp.u[6] = f2bf_rne(c.z * QSCALE);
            tmp.u[7] = f2bf_rne(c.w * QSCALE);
            qb[kc] = tmp.v;
        }
    }

    // ---- prefetch registers ----
    float4 kf[4];          // K tile: 4 coalesced float4 per thread
    float  vf[2][8];       // V gather: (d = lane, 8 consecutive keys) x 2 slots

    auto load_tile = [&](int it) {
        const float4* kg = (const float4*)(k + boff + (size_t)it * BC * DIM);
        #pragma unroll
        for (int i = 0; i < 4; i++) kf[i] = kg[t + 256 * i];
        const float* vgf = v + boff + (size_t)it * BC * DIM;
        #pragma unroll
        for (int i = 0; i < 2; i++) {
            int slot = t + 256 * i;
            int d = slot & 63, ko = slot >> 6;
            #pragma unroll
            for (int j = 0; j < 8; j++)
                vf[i][j] = vgf[(size_t)(ko * 8 + j) * DIM + d];
        }
    };

    auto stage = [&]() {
        #pragma unroll
        for (int i = 0; i < 4; i++) {
            int idx = t + 256 * i;
            int row = idx >> 4, c4 = idx & 15;
            uint2 w;
            w.x = pack2_trunc(kf[i].x, kf[i].y);
            w.y = pack2_trunc(kf[i].z, kf[i].w);
            *(uint2*)&KPs[row * LSTR + c4 * 4] = w;
        }
        #pragma unroll
        for (int i = 0; i < 2; i++) {
            int slot = t + 256 * i;
            int d = slot & 63, ko = slot >> 6;
            uint4 w;
            w.x = pack2_trunc(vf[i][0], vf[i][1]);
            w.y = pack2_trunc(vf[i][2], vf[i][3]);
            w.z = pack2_trunc(vf[i][4], vf[i][5]);
            w.w = pack2_trunc(vf[i][6], vf[i][7]);
            *(uint4*)&Vt[d * LSTR + ko * 8] = w;   // b128, bank-uniform
        }
    };

    float m_run = -INFINITY, l_run = 0.f;
    f32x4 acc[4];
    #pragma unroll
    for (int dt = 0; dt < 4; dt++) acc[dt] = (f32x4){0.f, 0.f, 0.f, 0.f};

    load_tile(it_begin);

    for (int it = it_begin; it < it_end; it++) {
        __syncthreads();                  // (A) prior tile's P/V LDS reads done
        stage();
        if (it + 1 < it_end) load_tile(it + 1);   // in flight across compute
        __syncthreads();                  // (B) staging visible

        // ---- S^T = K x Q^T : rows = keys (QD*4+r), cols = queries (li) ----
        f32x4 sc[4];
        #pragma unroll
        for (int kt = 0; kt < 4; kt++) {
            bf16x8 ka0 = *(const bf16x8*)&KPs[(kt * 16 + li) * LSTR + QD * 8];
            bf16x8 ka1 = *(const bf16x8*)&KPs[(kt * 16 + li) * LSTR + 32 + QD * 8];
            f32x4 c = (f32x4){0.f, 0.f, 0.f, 0.f};
            c = __builtin_amdgcn_mfma_f32_16x16x32_bf16(ka0, qb[0], c, 0, 0, 0);
            c = __builtin_amdgcn_mfma_f32_16x16x32_bf16(ka1, qb[1], c, 0, 0, 0);
            sc[kt] = c;
        }

        __syncthreads();                  // (C) all waves done reading K -> region becomes P

        // ---- mask (only the boundary/invalid tiles pay per-element cost) ----
        const int kbase = it * BC;
        if (kbase + BC > vl) {
            #pragma unroll
            for (int kt = 0; kt < 4; kt++)
                #pragma unroll
                for (int r = 0; r < 4; r++) {
                    int key = kbase + kt * 16 + QD * 4 + r;
                    if (key >= vl) sc[kt][r] = MASKED;
                }
        }

        // ---- online softmax in exp2 domain (row = query = li) ----
        float mt = -INFINITY;
        #pragma unroll
        for (int kt = 0; kt < 4; kt++)
            #pragma unroll
            for (int r = 0; r < 4; r++) mt = fmaxf(mt, sc[kt][r]);
        mt = fmaxf(mt, __shfl_xor(mt, 16, 64));
        mt = fmaxf(mt, __shfl_xor(mt, 32, 64));
        float mn = fmaxf(m_run, mt);
        float alpha = exp2f(m_run - mn);   // -inf on first tile -> 0
        m_run = mn;

        float ls = 0.f;
        #pragma unroll
        for (int kt = 0; kt < 4; kt++) {
            float p0 = exp2f(sc[kt][0] - mn);
            float p1 = exp2f(sc[kt][1] - mn);
            float p2 = exp2f(sc[kt][2] - mn);
            float p3 = exp2f(sc[kt][3] - mn);
            ls += (p0 + p1) + (p2 + p3);
            uint2 w;
            w.x = pack2_trunc(p0, p1);
            w.y = pack2_trunc(p2, p3);
            *(uint2*)&KPs[(wave * 16 + li) * LSTR + kt * 16 + QD * 4] = w;
        }
        ls += __shfl_xor(ls, 16, 64);
        ls += __shfl_xor(ls, 32, 64);
        l_run = l_run * alpha + ls;

        // rescale O accumulator rows (row = QD*4+r holds query QD*4+r)
        float a0 = __shfl(alpha, QD * 4 + 0, 64);
        float a1 = __shfl(alpha, QD * 4 + 1, 64);
        float a2 = __shfl(alpha, QD * 4 + 2, 64);
        float a3 = __shfl(alpha, QD * 4 + 3, 64);
        #pragma unroll
        for (int dt = 0; dt < 4; dt++) {
            acc[dt][0] *= a0; acc[dt][1] *= a1;
            acc[dt][2] *= a2; acc[dt][3] *= a3;
        }

        // ---- PV: O += P x V (same-wave LDS round-trip for P; P rows wave-private) ----
        bf16x8 pa0 = *(const bf16x8*)&KPs[(wave * 16 + li) * LSTR + QD * 8];
        bf16x8 pa1 = *(const bf16x8*)&KPs[(wave * 16 + li) * LSTR + 32 + QD * 8];
        #pragma unroll
        for (int dt = 0; dt < 4; dt++) {
            bf16x8 vb0 = *(const bf16x8*)&Vt[(dt * 16 + li) * LSTR + QD * 8];
            bf16x8 vb1 = *(const bf16x8*)&Vt[(dt * 16 + li) * LSTR + 32 + QD * 8];
            acc[dt] = __builtin_amdgcn_mfma_f32_16x16x32_bf16(pa0, vb0, acc[dt], 0, 0, 0);
            acc[dt] = __builtin_amdgcn_mfma_f32_16x16x32_bf16(pa1, vb1, acc[dt], 0, 0, 0);
        }
    }

    if (direct) {
        // ---- fast path: this item owns the whole softmax range ----
        float invl = 1.0f / l_run;
        float i0 = __shfl(invl, QD * 4 + 0, 64);
        float i1 = __shfl(invl, QD * 4 + 1, 64);
        float i2 = __shfl(invl, QD * 4 + 2, 64);
        float i3 = __shfl(invl, QD * 4 + 3, 64);
        float* ob = out + boff + (size_t)q0 * DIM;
        const int rbase = wave * 16 + QD * 4;
        #pragma unroll
        for (int dt = 0; dt < 4; dt++) {
            int col = dt * 16 + li;
            ob[(size_t)(rbase + 0) * DIM + col] = acc[dt][0] * i0;
            ob[(size_t)(rbase + 1) * DIM + col] = acc[dt][1] * i1;
            ob[(size_t)(rbase + 2) * DIM + col] = acc[dt][2] * i2;
            ob[(size_t)(rbase + 3) * DIM + col] = acc[dt][3] * i3;
        }
    } else {
        // ---- write UNNORMALIZED partial + (m,l); kernel2 combines ----
        if (QD == 0)
            lmbuf[(size_t)item * 64 + wave * 16 + li] = make_float2(m_run, l_run);
        float* ob = opart + (size_t)item * (BQ * DIM);
        const int rbase = wave * 16 + QD * 4;
        #pragma unroll
        for (int dt = 0; dt < 4; dt++) {
            int col = dt * 16 + li;
            ob[(size_t)(rbase + 0) * DIM + col] = acc[dt][0];
            ob[(size_t)(rbase + 1) * DIM + col] = acc[dt][1];
            ob[(size_t)(rbase + 2) * DIM + col] = acc[dt][2];
            ob[(size_t)(rbase + 3) * DIM + col] = acc[dt][3];
        }
    }
}

// ---- kernel 2: combine the two halves of pairs with it_full > HALFT ----
__global__ __launch_bounds__(256) void attn_combine(
    const int* __restrict__ valid_lens,
    const float2* __restrict__ lmbuf, const float* __restrict__ opart,
    float* __restrict__ out)
{
    const int pid = blockIdx.x;        // 0..1023
    const int b   = pid & 63;
    const int qt  = pid >> 6;
    const int vl  = valid_lens[b];
    const int it_full = (vl == 0) ? NKT : ((vl + BC - 1) >> 6);
    if (it_full <= HALFT) return;      // direct path already wrote out

    const int t  = threadIdx.x;
    const int qr = t >> 2;             // 64 query rows, 4 threads each
    const int c4 = t & 3;
    const int i1 = pid * 2;

    float2 ml1 = lmbuf[(size_t)i1 * 64 + qr];
    float2 ml2 = lmbuf[(size_t)(i1 + 1) * 64 + qr];
    float M  = fmaxf(ml1.x, ml2.x);
    float w1 = exp2f(ml1.x - M);
    float w2 = exp2f(ml2.x - M);
    float inv = 1.f / (ml1.y * w1 + ml2.y * w2);
    w1 *= inv; w2 *= inv;

    const float4* o1 = (const float4*)(opart + (size_t)i1 * (BQ * DIM));
    const float4* o2 = (const float4*)(opart + (size_t)(i1 + 1) * (BQ * DIM));
    float4* ob = (float4*)(out + ((size_t)b * SEQ + (size_t)qt * BQ) * DIM);
    #pragma unroll
    for (int j = 0; j < 4; j++) {
        int idx = qr * 16 + j * 4 + c4;   // lanes 0..3 cover 64 contiguous bytes
        float4 a  = o1[idx];
        float4 bb = o2[idx];
        float4 r;
        r.x = a.x * w1 + bb.x * w2;
        r.y = a.y * w1 + bb.y * w2;
        r.z = a.z * w1 + bb.z * w2;
        r.w = a.w * w1 + bb.w * w2;
        ob[idx] = r;
    }
}

// ---------------- fallback (no/short workspace): round-0 verified kernel, skewed ----------------
__global__ __launch_bounds__(256, 4) void attn_mfma_flash2(
    const float* __restrict__ q, const float* __restrict__ k,
    const float* __restrict__ v, const int* __restrict__ valid_lens,
    float* __restrict__ out)
{
    __shared__ ushort Ks[BC * LSTR];   // [key][d]
    __shared__ ushort Vt[DIM * LSTR];  // [d][key]
    __shared__ ushort Ps[BQ * LSTR];   // [query][key], wave-private 16-row bands

    const int t    = threadIdx.x;
    const int wave = t >> 6;
    const int wl   = t & 63;
    const int QD   = wl >> 4;
    const int li   = wl & 15;
    const int g    = blockIdx.x;
    const int grp  = g >> 6;
    const int b    = ((g & 63) + grp) & 63;   // de-aliased batch decode
    const int q0   = grp * BQ;
    const int vl   = valid_lens[b];

    const size_t boff = (size_t)b * SEQ * DIM;

    bf16x8 qb[2];
    {
        const float* qrow = q + boff + (size_t)(q0 + wave * 16 + li) * DIM + QD * 8;
        #pragma unroll
        for (int kc = 0; kc < 2; kc++) {
            float4 a = *(const float4*)(qrow + kc * 32);
            float4 c = *(const float4*)(qrow + kc * 32 + 4);
            union { bf16x8 v; ushort u[8]; } tmp;
            tmp.u[0] = f2bf_rne(a.x * QSCALE);
            tmp.u[1] = f2bf_rne(a.y * QSCALE);
            tmp.u[2] = f2bf_rne(a.z * QSCALE);
            tmp.u[3] = f2bf_rne(a.w * QSCALE);
            tmp.u[4] = f2bf_rne(c.x * QSCALE);
            tmp.u[5] = f2bf_rne(c.y * QSCALE);
            tmp.u[6] = f2bf_rne(c.z * QSCALE);
            tmp.u[7] = f2bf_rne(c.w * QSCALE);
            qb[kc] = tmp.v;
        }
    }

    const int it_max = (vl == 0) ? NKT : ((vl + BC - 1) >> 6);

    float4 kf[4];
    float  vf[2][8];

    auto load_tile = [&](int it) {
        const float4* kg = (const float4*)(k + boff + (size_t)it * BC * DIM);
        #pragma unroll
        for (int i = 0; i < 4; i++) kf[i] = kg[t + 256 * i];
        const float* vgf = v + boff + (size_t)it * BC * DIM;
        #pragma unroll
        for (int i = 0; i < 2; i++) {
            int slot = t + 256 * i;
            int d = slot & 63, ko = slot >> 6;
            #pragma unroll
            for (int j = 0; j < 8; j++)
                vf[i][j] = vgf[(size_t)(ko * 8 + j) * DIM + d];
        }
    };

    auto stage = [&]() {
        #pragma unroll
        for (int i = 0; i < 4; i++) {
            int idx = t + 256 * i;
            int row = idx >> 4, c4 = idx & 15;
            uint2 w;
            w.x = pack2_trunc(kf[i].x, kf[i].y);
            w.y = pack2_trunc(kf[i].z, kf[i].w);
            *(uint2*)&Ks[row * LSTR + c4 * 4] = w;
        }
        #pragma unroll
        for (int i = 0; i < 2; i++) {
            int slot = t + 256 * i;
            int d = slot & 63, ko = slot >> 6;
            uint4 w;
            w.x = pack2_trunc(vf[i][0], vf[i][1]);
            w.y = pack2_trunc(vf[i][2], vf[i][3]);
            w.z = pack2_trunc(vf[i][4], vf[i][5]);
            w.w = pack2_trunc(vf[i][6], vf[i][7]);
            *(uint4*)&Vt[d * LSTR + ko * 8] = w;
        }
    };

    float m_run = -INFINITY, l_run = 0.f;
    f32x4 acc[4];
    #pragma unroll
    for (int dt = 0; dt < 4; dt++) acc[dt] = (f32x4){0.f, 0.f, 0.f, 0.f};

    load_tile(0);

    for (int it = 0; it < it_max; it++) {
        __syncthreads();
        stage();
        if (it + 1 < it_max) load_tile(it + 1);
        __syncthreads();

        f32x4 sc[4];
        #pragma unroll
        for (int kt = 0; kt < 4; kt++) {
            bf16x8 ka0 = *(const bf16x8*)&Ks[(kt * 16 + li) * LSTR + QD * 8];
            bf16x8 ka1 = *(const bf16x8*)&Ks[(kt * 16 + li) * LSTR + 32 + QD * 8];
            f32x4 c = (f32x4){0.f, 0.f, 0.f, 0.f};
            c = __builtin_amdgcn_mfma_f32_16x16x32_bf16(ka0, qb[0], c, 0, 0, 0);
            c = __builtin_amdgcn_mfma_f32_16x16x32_bf16(ka1, qb[1], c, 0, 0, 0);
            sc[kt] = c;
        }

        const int kbase = it * BC;
        if (kbase + BC > vl) {
            #pragma unroll
            for (int kt = 0; kt < 4; kt++)
                #pragma unroll
                for (int r = 0; r < 4; r++) {
                    int key = kbase + kt * 16 + QD * 4 + r;
                    if (key >= vl) sc[kt][r] = MASKED;
                }
        }

        float mt = -INFINITY;
        #pragma unroll
        for (int kt = 0; kt < 4; kt++)
            #pragma unroll
            for (int r = 0; r < 4; r++) mt = fmaxf(mt, sc[kt][r]);
        mt = fmaxf(mt, __shfl_xor(mt, 16, 64));
        mt = fmaxf(mt, __shfl_xor(mt, 32, 64));
        float mn = fmaxf(m_run, mt);
        float alpha = exp2f(m_run - mn);
        m_run = mn;

        float ls = 0.f;
        #pragma unroll
        for (int kt = 0; kt < 4; kt++) {
            float p0 = exp2f(sc[kt][0] - mn);
            float p1 = exp2f(sc[kt][1] - mn);
            float p2 = exp2f(sc[kt][2] - mn);
            float p3 = exp2f(sc[kt][3] - mn);
            ls += (p0 + p1) + (p2 + p3);
            uint2 w;
            w.x = pack2_trunc(p0, p1);
            w.y = pack2_trunc(p2, p3);
            *(uint2*)&Ps[(wave * 16 + li) * LSTR + kt * 16 + QD * 4] = w;
        }
        ls += __shfl_xor(ls, 16, 64);
        ls += __shfl_xor(ls, 32, 64);
        l_run = l_run * alpha + ls;

        float a0 = __shfl(alpha, QD * 4 + 0, 64);
        float a1 = __shfl(alpha, QD * 4 + 1, 64);
        float a2 = __shfl(alpha, QD * 4 + 2, 64);
        float a3 = __shfl(alpha, QD * 4 + 3, 64);
        #pragma unroll
        for (int dt = 0; dt < 4; dt++) {
            acc[dt][0] *= a0; acc[dt][1] *= a1;
            acc[dt][2] *= a2; acc[dt][3] *= a3;
        }

        bf16x8 pa0 = *(const bf16x8*)&Ps[(wave * 16 + li) * LSTR + QD * 8];
        bf16x8 pa1 = *(const bf16x8*)&Ps[(wave * 16 + li) * LSTR + 32 + QD * 8];
        #pragma unroll
        for (int dt = 0; dt < 4; dt++) {
            bf16x8 vb0 = *(const bf16x8*)&Vt[(dt * 16 + li) * LSTR + QD * 8];
            bf16x8 vb1 = *(const bf16x8*)&Vt[(dt * 16 + li) * LSTR + 32 + QD * 8];
            acc[dt] = __builtin_amdgcn_mfma_f32_16x16x32_bf16(pa0, vb0, acc[dt], 0, 0, 0);
            acc[dt] = __builtin_amdgcn_mfma_f32_16x16x32_bf16(pa1, vb1, acc[dt], 0, 0, 0);
        }
    }

    float invl = 1.0f / l_run;
    float i0 = __shfl(invl, QD * 4 + 0, 64);
    float i1 = __shfl(invl, QD * 4 + 1, 64);
    float i2 = __shfl(invl, QD * 4 + 2, 64);
    float i3 = __shfl(invl, QD * 4 + 3, 64);
    float* ob = out + boff + (size_t)q0 * DIM;
    const int rbase = wave * 16 + QD * 4;
    #pragma unroll
    for (int dt = 0; dt < 4; dt++) {
        int col = dt * 16 + li;
        ob[(size_t)(rbase + 0) * DIM + col] = acc[dt][0] * i0;
        ob[(size_t)(rbase + 1) * DIM + col] = acc[dt][1] * i1;
        ob[(size_t)(rbase + 2) * DIM + col] = acc[dt][2] * i2;
        ob[(size_t)(rbase + 3) * DIM + col] = acc[dt][3] * i3;
    }
}

extern "C" void kernel_launch(void* const* d_in, const int* in_sizes, int n_in,
                              void* d_out, int out_size, void* d_ws, size_t ws_size,
                              hipStream_t stream) {
    const float* q = (const float*)d_in[0];
    const float* k = (const float*)d_in[1];
    const float* v = (const float*)d_in[2];
    const int* valid_lens = (const int*)d_in[3];
    float* out = (float*)d_out;

    if (d_ws != nullptr && ws_size >= WS_NEEDED) {
        float2* lmbuf = (float2*)d_ws;
        float*  opart = (float*)((char*)d_ws + WS_O_OFF);
        attn_mfma_splitk<<<dim3(BATCH * (SEQ / BQ) * 2), dim3(256), 0, stream>>>(
            q, k, v, valid_lens, out, lmbuf, opart);
        attn_combine<<<dim3(BATCH * (SEQ / BQ)), dim3(256), 0, stream>>>(
            valid_lens, lmbuf, opart, out);
    } else {
        dim3 grid(BATCH * (SEQ / BQ));       // 1024 blocks
        attn_mfma_flash2<<<grid, dim3(256), 0, stream>>>(q, k, v, valid_lens, out);
    }
}

// Round 6
// 127.940 us; speedup vs baseline: 1.0678x; 1.0678x over previous
//
#include <hip/hip_runtime.h>
#include <math.h>

// DotProductAttention B=64,S=1024,D=64 fp32, bf16-MFMA flash attention.
// Round 8: attack the per-iteration serial path. Evidence: dur invariant at
// ~54us across rounds 0/3/5 (1024-block, split-K, split-K+skew) with all
// pipes <30% -> not scheduling-bound; per-iteration critical path is the
// floor. Known mechanism (m97): __syncthreads() emits
// s_waitcnt vmcnt(0) lgkmcnt(0) before s_barrier -> our it+1 prefetch
// (20 VMEM insts issued right before barrier B) is fully drained BEFORE
// compute, so every iteration stalls the whole memory latency, x2 barriers.
// Fix (T3/T4 minimum 2-phase discipline):
//   barrier A: bare s_barrier           (reads already lgkm-drained by use)
//   barrier B: s_waitcnt lgkmcnt(0) ONLY -> vmcnt floats across the barrier;
//              prefetched loads drain at next iter's stage() reg-use, i.e.
//              after a full compute phase (~2000 cy) of cover.
//   sched_barrier(0) pins ds ops at both barriers (rule #18 / m201).
// Split-K + combine dropped (3 rounds proved scheduling-invariance; combine
// cost +8us). Round-0 math retained bit-for-bit (absmax 0.03125 proven).
// LDS 27.6 KB (Ks/Vt/Ps separate) -> 5 blocks/CU static; grid 1024 = 4/CU.

#define BATCH 64
#define SEQ   1024
#define DIM   64
#define BQ    64           // queries per block (4 waves x 16)
#define BC    64           // keys per iteration
#define NKT   (SEQ / BC)   // 16
#define LSTR  72           // LDS row stride in bf16 (144 B = 36 dwords === 4 mod 32)
#define QSCALE 0.18033688011112442f   // 0.125 * log2(e)
#define MASKED -1.0e6f

typedef __attribute__((ext_vector_type(8))) short bf16x8;
typedef __attribute__((ext_vector_type(4))) float f32x4;

__device__ __forceinline__ uint pack2_trunc(float lo, float hi) {
    // [bf16(hi) : bf16(lo)] by byte-select (truncation) — one v_perm_b32
    return __builtin_amdgcn_perm(__float_as_uint(hi), __float_as_uint(lo), 0x07060302);
}
__device__ __forceinline__ ushort f2bf_rne(float x) {
    uint u = __float_as_uint(x);
    return (ushort)((u + 0x7fffu + ((u >> 16) & 1u)) >> 16);
}

__global__ __launch_bounds__(256, 4) void attn_mfma_flash3(
    const float* __restrict__ q, const float* __restrict__ k,
    const float* __restrict__ v, const int* __restrict__ valid_lens,
    float* __restrict__ out)
{
    __shared__ ushort Ks[BC * LSTR];   // [key][d]
    __shared__ ushort Vt[DIM * LSTR];  // [d][key]
    __shared__ ushort Ps[BQ * LSTR];   // [query][key], wave-private 16-row bands

    const int t    = threadIdx.x;
    const int wave = t >> 6;
    const int wl   = t & 63;
    const int QD   = wl >> 4;          // quad 0..3
    const int li   = wl & 15;          // lane-in-quad 0..15
    // batch-major: all 16 q-tiles of a batch land on the same XCD (K/V L2-resident)
    const int b    = blockIdx.x & 63;
    const int q0   = (blockIdx.x >> 6) * BQ;
    const int vl   = valid_lens[b];

    const size_t boff = (size_t)b * SEQ * DIM;

    // ---- Q fragments straight into registers (B-operand), pre-scaled ----
    bf16x8 qb[2];
    {
        const float* qrow = q + boff + (size_t)(q0 + wave * 16 + li) * DIM + QD * 8;
        #pragma unroll
        for (int kc = 0; kc < 2; kc++) {
            float4 a = *(const float4*)(qrow + kc * 32);
            float4 c = *(const float4*)(qrow + kc * 32 + 4);
            union { bf16x8 v; ushort u[8]; } tmp;
            tmp.u[0] = f2bf_rne(a.x * QSCALE);
            tmp.u[1] = f2bf_rne(a.y * QSCALE);
            tmp.u[2] = f2bf_rne(a.z * QSCALE);
            tmp.u[3] = f2bf_rne(a.w * QSCALE);
            tmp.u[4] = f2bf_rne(c.x * QSCALE);
            tmp.u[5] = f2bf_rne(c.y * QSCALE);
            tmp.u[6] = f2bf_rne(c.z * QSCALE);
            tmp.u[7] = f2bf_rne(c.w * QSCALE);
            qb[kc] = tmp.v;
        }
    }

    const int it_max = (vl == 0) ? NKT : ((vl + BC - 1) >> 6);

    // ---- prefetch registers ----
    float4 kf[4];          // K tile: 4 coalesced float4 per thread
    float  vf[2][8];       // V gather: (d = lane, 8 consecutive keys) x 2 slots

    auto load_tile = [&](int it) {
        const float4* kg = (const float4*)(k + boff + (size_t)it * BC * DIM);
        #pragma unroll
        for (int i = 0; i < 4; i++) kf[i] = kg[t + 256 * i];
        const float* vgf = v + boff + (size_t)it * BC * DIM;
        #pragma unroll
        for (int i = 0; i < 2; i++) {
            int slot = t + 256 * i;
            int d = slot & 63, ko = slot >> 6;
            #pragma unroll
            for (int j = 0; j < 8; j++)
                vf[i][j] = vgf[(size_t)(ko * 8 + j) * DIM + d];
        }
    };

    auto stage = [&]() {
        #pragma unroll
        for (int i = 0; i < 4; i++) {
            int idx = t + 256 * i;
            int row = idx >> 4, c4 = idx & 15;
            uint2 w;
            w.x = pack2_trunc(kf[i].x, kf[i].y);
            w.y = pack2_trunc(kf[i].z, kf[i].w);
            *(uint2*)&Ks[row * LSTR + c4 * 4] = w;
        }
        #pragma unroll
        for (int i = 0; i < 2; i++) {
            int slot = t + 256 * i;
            int d = slot & 63, ko = slot >> 6;
            uint4 w;
            w.x = pack2_trunc(vf[i][0], vf[i][1]);
            w.y = pack2_trunc(vf[i][2], vf[i][3]);
            w.z = pack2_trunc(vf[i][4], vf[i][5]);
            w.w = pack2_trunc(vf[i][6], vf[i][7]);
            *(uint4*)&Vt[d * LSTR + ko * 8] = w;   // b128, bank-uniform
        }
    };

    float m_run = -INFINITY, l_run = 0.f;
    f32x4 acc[4];
    #pragma unroll
    for (int dt = 0; dt < 4; dt++) acc[dt] = (f32x4){0.f, 0.f, 0.f, 0.f};

    load_tile(0);

    for (int it = 0; it < it_max; it++) {
        // ---- barrier A: all waves done reading Ks/Vt of previous tile ----
        // Their ds_read results were consumed by MFMAs before arriving here,
        // so lgkmcnt is already drained per-wave; bare s_barrier suffices.
        // sched_barrier(0) fences keep ds ops from crossing (rule #18/m201).
        __builtin_amdgcn_sched_barrier(0);
        __builtin_amdgcn_s_barrier();
        __builtin_amdgcn_sched_barrier(0);

        stage();                                   // regs (loaded last iter) -> LDS
        if (it + 1 < it_max) load_tile(it + 1);    // issue next-tile loads; vmcnt FLOATS

        // ---- barrier B: staging visible. lgkmcnt(0) only — vmcnt NOT drained,
        // so the it+1 global loads stay in flight across the barrier and hide
        // under this iteration's whole compute phase. ----
        __builtin_amdgcn_sched_barrier(0);
        asm volatile("s_waitcnt lgkmcnt(0)" ::: "memory");
        __builtin_amdgcn_s_barrier();
        __builtin_amdgcn_sched_barrier(0);

        // ---- S^T = K x Q^T : rows = keys (QD*4+r), cols = queries (li) ----
        f32x4 sc[4];
        #pragma unroll
        for (int kt = 0; kt < 4; kt++) {
            bf16x8 ka0 = *(const bf16x8*)&Ks[(kt * 16 + li) * LSTR + QD * 8];
            bf16x8 ka1 = *(const bf16x8*)&Ks[(kt * 16 + li) * LSTR + 32 + QD * 8];
            f32x4 c = (f32x4){0.f, 0.f, 0.f, 0.f};
            c = __builtin_amdgcn_mfma_f32_16x16x32_bf16(ka0, qb[0], c, 0, 0, 0);
            c = __builtin_amdgcn_mfma_f32_16x16x32_bf16(ka1, qb[1], c, 0, 0, 0);
            sc[kt] = c;
        }

        // ---- mask (only the boundary/invalid tiles pay per-element cost) ----
        const int kbase = it * BC;
        if (kbase + BC > vl) {
            #pragma unroll
            for (int kt = 0; kt < 4; kt++)
                #pragma unroll
                for (int r = 0; r < 4; r++) {
                    int key = kbase + kt * 16 + QD * 4 + r;
                    if (key >= vl) sc[kt][r] = MASKED;
                }
        }

        // ---- online softmax in exp2 domain (row = query = li) ----
        float mt = -INFINITY;
        #pragma unroll
        for (int kt = 0; kt < 4; kt++)
            #pragma unroll
            for (int r = 0; r < 4; r++) mt = fmaxf(mt, sc[kt][r]);
        mt = fmaxf(mt, __shfl_xor(mt, 16, 64));
        mt = fmaxf(mt, __shfl_xor(mt, 32, 64));
        float mn = fmaxf(m_run, mt);
        float alpha = exp2f(m_run - mn);   // -inf on first tile -> 0
        m_run = mn;

        float ls = 0.f;
        #pragma unroll
        for (int kt = 0; kt < 4; kt++) {
            float p0 = exp2f(sc[kt][0] - mn);
            float p1 = exp2f(sc[kt][1] - mn);
            float p2 = exp2f(sc[kt][2] - mn);
            float p3 = exp2f(sc[kt][3] - mn);
            ls += (p0 + p1) + (p2 + p3);
            uint2 w;
            w.x = pack2_trunc(p0, p1);
            w.y = pack2_trunc(p2, p3);
            *(uint2*)&Ps[(wave * 16 + li) * LSTR + kt * 16 + QD * 4] = w;
        }
        ls += __shfl_xor(ls, 16, 64);
        ls += __shfl_xor(ls, 32, 64);
        l_run = l_run * alpha + ls;

        // rescale O accumulator rows (row = QD*4+r holds query QD*4+r)
        float a0 = __shfl(alpha, QD * 4 + 0, 64);
        float a1 = __shfl(alpha, QD * 4 + 1, 64);
        float a2 = __shfl(alpha, QD * 4 + 2, 64);
        float a3 = __shfl(alpha, QD * 4 + 3, 64);
        #pragma unroll
        for (int dt = 0; dt < 4; dt++) {
            acc[dt][0] *= a0; acc[dt][1] *= a1;
            acc[dt][2] *= a2; acc[dt][3] *= a3;
        }

        // ---- PV: O += P x V (same-wave LDS round-trip for P; P rows are
        // wave-private -> no barrier; lgkm data-dep orders write->read) ----
        bf16x8 pa0 = *(const bf16x8*)&Ps[(wave * 16 + li) * LSTR + QD * 8];
        bf16x8 pa1 = *(const bf16x8*)&Ps[(wave * 16 + li) * LSTR + 32 + QD * 8];
        #pragma unroll
        for (int dt = 0; dt < 4; dt++) {
            bf16x8 vb0 = *(const bf16x8*)&Vt[(dt * 16 + li) * LSTR + QD * 8];
            bf16x8 vb1 = *(const bf16x8*)&Vt[(dt * 16 + li) * LSTR + 32 + QD * 8];
            acc[dt] = __builtin_amdgcn_mfma_f32_16x16x32_bf16(pa0, vb0, acc[dt], 0, 0, 0);
            acc[dt] = __builtin_amdgcn_mfma_f32_16x16x32_bf16(pa1, vb1, acc[dt], 0, 0, 0);
        }
    }

    // ---- epilogue ----
    float invl = 1.0f / l_run;
    float i0 = __shfl(invl, QD * 4 + 0, 64);
    float i1 = __shfl(invl, QD * 4 + 1, 64);
    float i2 = __shfl(invl, QD * 4 + 2, 64);
    float i3 = __shfl(invl, QD * 4 + 3, 64);
    float* ob = out + boff + (size_t)q0 * DIM;
    const int rbase = wave * 16 + QD * 4;
    #pragma unroll
    for (int dt = 0; dt < 4; dt++) {
        int col = dt * 16 + li;
        ob[(size_t)(rbase + 0) * DIM + col] = acc[dt][0] * i0;
        ob[(size_t)(rbase + 1) * DIM + col] = acc[dt][1] * i1;
        ob[(size_t)(rbase + 2) * DIM + col] = acc[dt][2] * i2;
        ob[(size_t)(rbase + 3) * DIM + col] = acc[dt][3] * i3;
    }
}

extern "C" void kernel_launch(void* const* d_in, const int* in_sizes, int n_in,
                              void* d_out, int out_size, void* d_ws, size_t ws_size,
                              hipStream_t stream) {
    const float* q = (const float*)d_in[0];
    const float* k = (const float*)d_in[1];
    const float* v = (const float*)d_in[2];
    const int* valid_lens = (const int*)d_in[3];
    float* out = (float*)d_out;

    dim3 grid(BATCH * (SEQ / BQ));   // 64 x 16 = 1024 blocks
    dim3 block(256);
    attn_mfma_flash3<<<grid, block, 0, stream>>>(q, k, v, valid_lens, out);
}

// Round 7
// 124.366 us; speedup vs baseline: 1.0985x; 1.0287x over previous
//
#include <hip/hip_runtime.h>
#include <math.h>

// DotProductAttention B=64,S=1024,D=64 fp32, bf16-MFMA flash attention.
// Round 9: cut per-iteration LDS work (the one thing invariant across four
// null experiments: baseline=splitK=skew=counted-vmcnt=54us). Straggler CU
// = 64 block-iters in 127K cy -> 2000cy/block-iter, of which ~1700cy is LDS
// pipe (stage 16xb64w+8xb128w, QK 32xb128r, softmax 16xb64w+32xbperm,
// PV 40xb128r + 360cy measured conflicts) -> LDS pipe is the saturated
// shared resource; extra blocks just queue (why splitK/skew were null).
// Changes:
//  1) P-IN-REGISTER via key-slot permutation: PV sums over keys, so permute
//     keys identically in P and V. slot(k)=(kt&1)*32+QD*8+(kt>>1)*4+r makes
//     each lane's 16 softmax values exactly its PV A-fragments (pa0=sc0,sc2;
//     pa1=sc1,sc3 packed). V staging gathers permuted rows. Ps buffer
//     DELETED: -4 b64w -2 b128r per wave/iter + removes write->read serial
//     latency. LDS 27.6 -> 18.4 KB.
//  2) DEFER-RESCALE (T13, THR=8): skip alpha path (4 bpermute + 16 VALU)
//     when __all(mt - m_run <= 8); P bounded by 2^8, f32 l/acc fine.
// Barrier discipline kept from round 8 (neutral, not harmful): bare
// s_barrier at A; lgkmcnt(0)-only at B (vmcnt floats across).

#define BATCH 64
#define SEQ   1024
#define DIM   64
#define BQ    64           // queries per block (4 waves x 16)
#define BC    64           // keys per iteration
#define NKT   (SEQ / BC)   // 16
#define LSTR  72           // LDS row stride in bf16 (144 B)
#define QSCALE 0.18033688011112442f   // 0.125 * log2(e)
#define MASKED -1.0e6f
#define THR    8.0f        // defer-rescale threshold (exp2 domain)

typedef __attribute__((ext_vector_type(8))) short bf16x8;
typedef __attribute__((ext_vector_type(4))) float f32x4;

__device__ __forceinline__ uint pack2_trunc(float lo, float hi) {
    // [bf16(hi) : bf16(lo)] by byte-select (truncation) — one v_perm_b32
    return __builtin_amdgcn_perm(__float_as_uint(hi), __float_as_uint(lo), 0x07060302);
}
__device__ __forceinline__ ushort f2bf_rne(float x) {
    uint u = __float_as_uint(x);
    return (ushort)((u + 0x7fffu + ((u >> 16) & 1u)) >> 16);
}

__global__ __launch_bounds__(256, 4) void attn_mfma_flash4(
    const float* __restrict__ q, const float* __restrict__ k,
    const float* __restrict__ v, const int* __restrict__ valid_lens,
    float* __restrict__ out)
{
    __shared__ ushort Ks[BC * LSTR];   // [key][d]
    __shared__ ushort Vt[DIM * LSTR];  // [d][slot]  (slot = permuted key)

    const int t    = threadIdx.x;
    const int wave = t >> 6;
    const int wl   = t & 63;
    const int QD   = wl >> 4;          // quad 0..3
    const int li   = wl & 15;          // lane-in-quad 0..15
    // batch-major: all 16 q-tiles of a batch land on the same XCD
    const int b    = blockIdx.x & 63;
    const int q0   = (blockIdx.x >> 6) * BQ;
    const int vl   = valid_lens[b];

    const size_t boff = (size_t)b * SEQ * DIM;

    // ---- Q fragments straight into registers (B-operand), pre-scaled ----
    bf16x8 qb[2];
    {
        const float* qrow = q + boff + (size_t)(q0 + wave * 16 + li) * DIM + QD * 8;
        #pragma unroll
        for (int kc = 0; kc < 2; kc++) {
            float4 a = *(const float4*)(qrow + kc * 32);
            float4 c = *(const float4*)(qrow + kc * 32 + 4);
            union { bf16x8 v; ushort u[8]; } tmp;
            tmp.u[0] = f2bf_rne(a.x * QSCALE);
            tmp.u[1] = f2bf_rne(a.y * QSCALE);
            tmp.u[2] = f2bf_rne(a.z * QSCALE);
            tmp.u[3] = f2bf_rne(a.w * QSCALE);
            tmp.u[4] = f2bf_rne(c.x * QSCALE);
            tmp.u[5] = f2bf_rne(c.y * QSCALE);
            tmp.u[6] = f2bf_rne(c.z * QSCALE);
            tmp.u[7] = f2bf_rne(c.w * QSCALE);
            qb[kc] = tmp.v;
        }
    }

    const int it_max = (vl == 0) ? NKT : ((vl + BC - 1) >> 6);

    // ---- prefetch registers ----
    float4 kf[4];          // K tile: 4 coalesced float4 per thread
    float  vf[2][8];       // V gather: (d = lane, 8 slot-ordered keys) x 2

    // V slot permutation: slot sigma = ko*8+j holds original key
    //   key = ((ko>>2) + ((j>>2)<<1))*16 + (ko&3)*4 + (j&3)
    // i.e. rows {kb..kb+3, kb+32..kb+35}, kb = (ko>>2)*16 + (ko&3)*4.
    auto load_tile = [&](int it) {
        const float4* kg = (const float4*)(k + boff + (size_t)it * BC * DIM);
        #pragma unroll
        for (int i = 0; i < 4; i++) kf[i] = kg[t + 256 * i];
        const float* vgf = v + boff + (size_t)it * BC * DIM;
        #pragma unroll
        for (int i = 0; i < 2; i++) {
            int slot = t + 256 * i;
            int d = slot & 63, ko = slot >> 6;
            int kb = (ko >> 2) * 16 + (ko & 3) * 4;
            #pragma unroll
            for (int j = 0; j < 8; j++) {
                int kk = kb + ((j >> 2) << 5) + (j & 3);
                vf[i][j] = vgf[(size_t)kk * DIM + d];
            }
        }
    };

    auto stage = [&]() {
        #pragma unroll
        for (int i = 0; i < 4; i++) {
            int idx = t + 256 * i;
            int row = idx >> 4, c4 = idx & 15;
            uint2 w;
            w.x = pack2_trunc(kf[i].x, kf[i].y);
            w.y = pack2_trunc(kf[i].z, kf[i].w);
            *(uint2*)&Ks[row * LSTR + c4 * 4] = w;
        }
        #pragma unroll
        for (int i = 0; i < 2; i++) {
            int slot = t + 256 * i;
            int d = slot & 63, ko = slot >> 6;
            uint4 w;
            w.x = pack2_trunc(vf[i][0], vf[i][1]);
            w.y = pack2_trunc(vf[i][2], vf[i][3]);
            w.z = pack2_trunc(vf[i][4], vf[i][5]);
            w.w = pack2_trunc(vf[i][6], vf[i][7]);
            *(uint4*)&Vt[d * LSTR + ko * 8] = w;   // b128 row write
        }
    };

    float m_run = -INFINITY, l_run = 0.f;
    f32x4 acc[4];
    #pragma unroll
    for (int dt = 0; dt < 4; dt++) acc[dt] = (f32x4){0.f, 0.f, 0.f, 0.f};

    load_tile(0);

    for (int it = 0; it < it_max; it++) {
        // barrier A: all waves done reading Ks/Vt of previous tile
        __builtin_amdgcn_sched_barrier(0);
        __builtin_amdgcn_s_barrier();
        __builtin_amdgcn_sched_barrier(0);

        stage();
        if (it + 1 < it_max) load_tile(it + 1);    // vmcnt floats across barrier B

        // barrier B: staging visible (lgkm only)
        __builtin_amdgcn_sched_barrier(0);
        asm volatile("s_waitcnt lgkmcnt(0)" ::: "memory");
        __builtin_amdgcn_s_barrier();
        __builtin_amdgcn_sched_barrier(0);

        // ---- S^T = K x Q^T : rows = keys (QD*4+r), cols = queries (li) ----
        f32x4 sc[4];
        #pragma unroll
        for (int kt = 0; kt < 4; kt++) {
            bf16x8 ka0 = *(const bf16x8*)&Ks[(kt * 16 + li) * LSTR + QD * 8];
            bf16x8 ka1 = *(const bf16x8*)&Ks[(kt * 16 + li) * LSTR + 32 + QD * 8];
            f32x4 c = (f32x4){0.f, 0.f, 0.f, 0.f};
            c = __builtin_amdgcn_mfma_f32_16x16x32_bf16(ka0, qb[0], c, 0, 0, 0);
            c = __builtin_amdgcn_mfma_f32_16x16x32_bf16(ka1, qb[1], c, 0, 0, 0);
            sc[kt] = c;
        }

        // ---- mask (only boundary/invalid tiles pay per-element cost) ----
        const int kbase = it * BC;
        if (kbase + BC > vl) {
            #pragma unroll
            for (int kt = 0; kt < 4; kt++)
                #pragma unroll
                for (int r = 0; r < 4; r++) {
                    int key = kbase + kt * 16 + QD * 4 + r;
                    if (key >= vl) sc[kt][r] = MASKED;
                }
        }

        // ---- online softmax, exp2 domain, defer-rescale (THR=8) ----
        float mt = -INFINITY;
        #pragma unroll
        for (int kt = 0; kt < 4; kt++)
            #pragma unroll
            for (int r = 0; r < 4; r++) mt = fmaxf(mt, sc[kt][r]);
        mt = fmaxf(mt, __shfl_xor(mt, 16, 64));
        mt = fmaxf(mt, __shfl_xor(mt, 32, 64));

        if (!__all(mt - m_run <= THR)) {
            // rescale path (~1 of 16 iters): update m, scale acc and l
            float mn = fmaxf(m_run, mt);
            float alpha = exp2f(m_run - mn);   // -inf on first tile -> 0
            m_run = mn;
            l_run *= alpha;
            float a0 = __shfl(alpha, QD * 4 + 0, 64);
            float a1 = __shfl(alpha, QD * 4 + 1, 64);
            float a2 = __shfl(alpha, QD * 4 + 2, 64);
            float a3 = __shfl(alpha, QD * 4 + 3, 64);
            #pragma unroll
            for (int dt = 0; dt < 4; dt++) {
                acc[dt][0] *= a0; acc[dt][1] *= a1;
                acc[dt][2] *= a2; acc[dt][3] *= a3;
            }
        }

        // ---- P in registers: p(kt,r) -> slot (kt&1)*32 + QD*8 + (kt>>1)*4 + r
        // pa0 = packed sc[0],sc[2]; pa1 = packed sc[1],sc[3]. ----
        float ls = 0.f;
        union { bf16x8 v; uint u[4]; } pa0u, pa1u;
        {
            float p00 = exp2f(sc[0][0] - m_run), p01 = exp2f(sc[0][1] - m_run);
            float p02 = exp2f(sc[0][2] - m_run), p03 = exp2f(sc[0][3] - m_run);
            float p10 = exp2f(sc[1][0] - m_run), p11 = exp2f(sc[1][1] - m_run);
            float p12 = exp2f(sc[1][2] - m_run), p13 = exp2f(sc[1][3] - m_run);
            float p20 = exp2f(sc[2][0] - m_run), p21 = exp2f(sc[2][1] - m_run);
            float p22 = exp2f(sc[2][2] - m_run), p23 = exp2f(sc[2][3] - m_run);
            float p30 = exp2f(sc[3][0] - m_run), p31 = exp2f(sc[3][1] - m_run);
            float p32 = exp2f(sc[3][2] - m_run), p33 = exp2f(sc[3][3] - m_run);
            ls = ((p00 + p01) + (p02 + p03)) + ((p10 + p11) + (p12 + p13))
               + ((p20 + p21) + (p22 + p23)) + ((p30 + p31) + (p32 + p33));
            pa0u.u[0] = pack2_trunc(p00, p01);
            pa0u.u[1] = pack2_trunc(p02, p03);
            pa0u.u[2] = pack2_trunc(p20, p21);
            pa0u.u[3] = pack2_trunc(p22, p23);
            pa1u.u[0] = pack2_trunc(p10, p11);
            pa1u.u[1] = pack2_trunc(p12, p13);
            pa1u.u[2] = pack2_trunc(p30, p31);
            pa1u.u[3] = pack2_trunc(p32, p33);
        }
        ls += __shfl_xor(ls, 16, 64);
        ls += __shfl_xor(ls, 32, 64);
        l_run += ls;

        // ---- PV: O += P x V(slot-permuted), P straight from registers ----
        #pragma unroll
        for (int dt = 0; dt < 4; dt++) {
            bf16x8 vb0 = *(const bf16x8*)&Vt[(dt * 16 + li) * LSTR + QD * 8];
            bf16x8 vb1 = *(const bf16x8*)&Vt[(dt * 16 + li) * LSTR + 32 + QD * 8];
            acc[dt] = __builtin_amdgcn_mfma_f32_16x16x32_bf16(pa0u.v, vb0, acc[dt], 0, 0, 0);
            acc[dt] = __builtin_amdgcn_mfma_f32_16x16x32_bf16(pa1u.v, vb1, acc[dt], 0, 0, 0);
        }
    }

    // ---- epilogue ----
    float invl = 1.0f / l_run;
    float i0 = __shfl(invl, QD * 4 + 0, 64);
    float i1 = __shfl(invl, QD * 4 + 1, 64);
    float i2 = __shfl(invl, QD * 4 + 2, 64);
    float i3 = __shfl(invl, QD * 4 + 3, 64);
    float* ob = out + boff + (size_t)q0 * DIM;
    const int rbase = wave * 16 + QD * 4;
    #pragma unroll
    for (int dt = 0; dt < 4; dt++) {
        int col = dt * 16 + li;
        ob[(size_t)(rbase + 0) * DIM + col] = acc[dt][0] * i0;
        ob[(size_t)(rbase + 1) * DIM + col] = acc[dt][1] * i1;
        ob[(size_t)(rbase + 2) * DIM + col] = acc[dt][2] * i2;
        ob[(size_t)(rbase + 3) * DIM + col] = acc[dt][3] * i3;
    }
}

extern "C" void kernel_launch(void* const* d_in, const int* in_sizes, int n_in,
                              void* d_out, int out_size, void* d_ws, size_t ws_size,
                              hipStream_t stream) {
    const float* q = (const float*)d_in[0];
    const float* k = (const float*)d_in[1];
    const float* v = (const float*)d_in[2];
    const int* valid_lens = (const int*)d_in[3];
    float* out = (float*)d_out;

    dim3 grid(BATCH * (SEQ / BQ));   // 64 x 16 = 1024 blocks
    dim3 block(256);
    attn_mfma_flash4<<<grid, block, 0, stream>>>(q, k, v, valid_lens, out);
}